// Round 1
// baseline (3386.111 us; speedup 1.0000x reference)
//
#include <hip/hip_runtime.h>
#include <cstddef>
#include <cstdint>

// Shapes: B=2, C=8, L=512, CH=256, CW=8, NH=8, head_dim=256, ROT=32.
// x:        [2,8,512,256,8]  f32
// prev_qk:  [2,8,8,512,512]  f32
// conv_*_w: [8,8,3,3]
// wq/wk/wv/wo: [8,256,256]
// out0: [2,8,512,256,8] (16777216 f32), out1 qk: [2,8,8,512,512] (16777216 f32)

// ---------------- weight transpose: wt[c][h][g] = w[c][g][h] ----------------
__global__ __launch_bounds__(256) void transpose_w_kernel(
    const float* __restrict__ wq, const float* __restrict__ wk,
    const float* __restrict__ wv, const float* __restrict__ wo,
    float* __restrict__ wt) {
  int mat = blockIdx.y;
  const float* src = (mat == 0) ? wq : (mat == 1) ? wk : (mat == 2) ? wv : wo;
  float* dst = wt + (size_t)mat * 524288;
  int idx = blockIdx.x * 256 + threadIdx.x;   // 0..524287
  int c = idx >> 16;
  int h = (idx >> 8) & 255;
  int g = idx & 255;
  dst[idx] = src[((size_t)c << 16) + (g << 8) + h];
}

// ---------------- conv 3x3, pad 1, 8->8 channels over (256,8) spatial -------
// h[bl,ci,i,j] = x[b,ci,l,i,j]; out[bl,co,i,j] flat idx matches thread idx.
__global__ __launch_bounds__(256) void conv_kernel(const float* __restrict__ x,
                                                   const float* __restrict__ w,
                                                   float* __restrict__ out) {
  __shared__ float wl[576];
  for (int t = threadIdx.x; t < 576; t += 256) wl[t] = w[t];
  __syncthreads();
  int idx = blockIdx.x * 256 + threadIdx.x;   // 16,777,216 total
  int j  = idx & 7;
  int i  = (idx >> 3) & 255;
  int co = (idx >> 11) & 7;
  int bl = idx >> 14;                          // b*512 + l
  int b  = bl >> 9;
  int l  = bl & 511;
  float acc = 0.f;
  for (int ci = 0; ci < 8; ++ci) {
    const float* xc = x + (((size_t)(b * 8 + ci) * 512 + l) << 11);
    const float* wc = wl + (co * 8 + ci) * 9;
#pragma unroll
    for (int di = 0; di < 3; ++di) {
      int i2 = i + di - 1;
      if (i2 < 0 || i2 > 255) continue;
#pragma unroll
      for (int dj = 0; dj < 3; ++dj) {
        int j2 = j + dj - 1;
        if (j2 < 0 || j2 > 7) continue;
        acc += xc[(i2 << 3) + j2] * wc[di * 3 + dj];
      }
    }
  }
  out[idx] = acc;
}

// ---------------- mlin: out[bl,c,g,w] = sum_h in[bl,c,h,w] * W[c,g,h] -------
// MODE 0: write q/k/v head layout q[((b*8+c)*8+n)*131072 + l*256 + d], f=g*8+w,
//         n=f>>8, d=f&255.
// MODE 1: write out[b,c,l,g,w] = out[(((b*8+c)*512+l)*256+g)*8+w].
template <int MODE>
__global__ __launch_bounds__(256) void mlin_kernel(const float* __restrict__ in,
                                                   const float* __restrict__ wt,
                                                   float* __restrict__ out) {
  __shared__ float lds[2304];                 // 2048 input tile / 256*9 transpose
  int blc = blockIdx.x;                       // bl*8 + c
  int c  = blc & 7;
  int bl = blc >> 3;
  int b  = bl >> 9;
  int l  = bl & 511;
  const float* inb = in + ((size_t)blc << 11);
  for (int t = threadIdx.x; t < 2048; t += 256) lds[t] = inb[t];
  __syncthreads();
  int g = threadIdx.x;
  const float* wtc = wt + ((size_t)c << 16) + g;   // wt[c][h][g], stride 256 in h
  float acc[8];
#pragma unroll
  for (int w = 0; w < 8; ++w) acc[w] = 0.f;
  for (int h = 0; h < 256; ++h) {
    float wv = wtc[h << 8];
    float4 i0 = *(const float4*)&lds[h << 3];
    float4 i1 = *(const float4*)&lds[(h << 3) + 4];
    acc[0] += i0.x * wv; acc[1] += i0.y * wv;
    acc[2] += i0.z * wv; acc[3] += i0.w * wv;
    acc[4] += i1.x * wv; acc[5] += i1.y * wv;
    acc[6] += i1.z * wv; acc[7] += i1.w * wv;
  }
  __syncthreads();
#pragma unroll
  for (int w = 0; w < 8; ++w) lds[g * 9 + w] = acc[w];
  __syncthreads();
  if (MODE == 0) {
    size_t ob = ((size_t)(b * 8 + c) << 3);
    for (int t = threadIdx.x; t < 2048; t += 256) {
      int n = t >> 8, d = t & 255;
      out[((ob + n) << 17) + (l << 8) + d] = lds[(t >> 3) * 9 + (t & 7)];
    }
  } else {
    float* ob = out + (((size_t)(b * 8 + c) * 512 + l) << 11);
    for (int t = threadIdx.x; t < 2048; t += 256) ob[t] = lds[(t >> 3) * 9 + (t & 7)];
  }
}

// ---------------- RoPE in-place on first 32 dims of each head ---------------
__global__ __launch_bounds__(256) void rope_kernel(float* __restrict__ xq) {
  int idx = blockIdx.x * 256 + threadIdx.x;   // 128 heads * 512 l * 16 pairs
  int t  = idx & 15;
  int l  = (idx >> 4) & 511;
  int hd = idx >> 13;                          // 0..127
  size_t a = ((size_t)hd << 17) + ((size_t)l << 8) + 2 * t;
  float inv = powf(10000.0f, -(float)(2 * t) / 32.0f);
  float ang = (float)l * inv;
  float cv = cosf(ang), sv = sinf(ang);
  float x0 = xq[a], x1 = xq[a + 1];
  xq[a]     = x0 * cv - x1 * sv;
  xq[a + 1] = x1 * cv + x0 * sv;
}

// ---------------- attention: per head, 8 query rows per block ---------------
// s = q@k^T/16 + prev  (written to qk_out), p = softmax(s), a = p@v
// a written in output-mlin input layout: a2[(bl*8+c)*2048 + n*256 + d]
__global__ __launch_bounds__(256) void attn_kernel(
    const float* __restrict__ q, const float* __restrict__ k,
    const float* __restrict__ v, const float* __restrict__ prev,
    float* __restrict__ qk_out, float* __restrict__ a2) {
  __shared__ float q_lds[8][256];
  __shared__ float s_lds[8][512];
  __shared__ float redbuf[4][8];
  int head = blockIdx.x >> 6;                  // ((b*8+c)*8+n)
  int l0 = (blockIdx.x & 63) << 3;
  int b = head >> 6, c = (head >> 3) & 7, n = head & 7;
  size_t base  = (size_t)head << 17;           // *131072 (q/k/v)
  size_t pbase = (size_t)head << 18;           // *262144 (prev/qk)
  int tid = threadIdx.x, lane = tid & 63, wid = tid >> 6;

  for (int t = tid; t < 2048; t += 256)
    q_lds[t >> 8][t & 255] = q[base + ((size_t)(l0 + (t >> 8)) << 8) + (t & 255)];
  __syncthreads();

  // ---- S = Q K^T : thread handles columns m1=tid, m2=tid+256 ----
  float acc1[8], acc2[8];
#pragma unroll
  for (int r = 0; r < 8; ++r) { acc1[r] = 0.f; acc2[r] = 0.f; }
  const float* k1 = k + base + ((size_t)tid << 8);
  const float* k2 = k1 + (256 << 8);
  for (int h = 0; h < 256; h += 4) {
    float4 kv1 = *(const float4*)(k1 + h);
    float4 kv2 = *(const float4*)(k2 + h);
#pragma unroll
    for (int r = 0; r < 8; ++r) {
      float4 qv = *(const float4*)&q_lds[r][h];
      acc1[r] += qv.x * kv1.x + qv.y * kv1.y + qv.z * kv1.z + qv.w * kv1.w;
      acc2[r] += qv.x * kv2.x + qv.y * kv2.y + qv.z * kv2.z + qv.w * kv2.w;
    }
  }

  // ---- scale + prev, emit qk_out, keep in registers ----
  float s1[8], s2[8];
#pragma unroll
  for (int r = 0; r < 8; ++r) {
    size_t prow = pbase + ((size_t)(l0 + r) << 9);
    float v1 = acc1[r] * 0.0625f + prev[prow + tid];
    float v2 = acc2[r] * 0.0625f + prev[prow + tid + 256];
    qk_out[prow + tid] = v1;
    qk_out[prow + tid + 256] = v2;
    s1[r] = v1; s2[r] = v2;
  }

  // ---- softmax: block max ----
#pragma unroll
  for (int r = 0; r < 8; ++r) {
    float m = fmaxf(s1[r], s2[r]);
    for (int off = 32; off; off >>= 1) m = fmaxf(m, __shfl_xor(m, off));
    if (lane == 0) redbuf[wid][r] = m;
  }
  __syncthreads();
  float mx[8];
#pragma unroll
  for (int r = 0; r < 8; ++r)
    mx[r] = fmaxf(fmaxf(redbuf[0][r], redbuf[1][r]),
                  fmaxf(redbuf[2][r], redbuf[3][r]));
  __syncthreads();   // redbuf reuse

  // ---- exp + block sum; e stored into s_lds ----
#pragma unroll
  for (int r = 0; r < 8; ++r) {
    float e1 = __expf(s1[r] - mx[r]);
    float e2 = __expf(s2[r] - mx[r]);
    s_lds[r][tid] = e1;
    s_lds[r][tid + 256] = e2;
    float s = e1 + e2;
    for (int off = 32; off; off >>= 1) s += __shfl_xor(s, off);
    if (lane == 0) redbuf[wid][r] = s;
  }
  __syncthreads();
  float rinv[8];
#pragma unroll
  for (int r = 0; r < 8; ++r)
    rinv[r] = 1.0f / (redbuf[0][r] + redbuf[1][r] + redbuf[2][r] + redbuf[3][r]);

  // ---- A = P V : thread owns output dim d=tid ----
  int d = tid;
  float pacc[8];
#pragma unroll
  for (int r = 0; r < 8; ++r) pacc[r] = 0.f;
  const float* vp = v + base + d;
  for (int m = 0; m < 512; m += 4) {
    float vv0 = vp[(size_t)m << 8];
    float vv1 = vp[(size_t)(m + 1) << 8];
    float vv2 = vp[(size_t)(m + 2) << 8];
    float vv3 = vp[(size_t)(m + 3) << 8];
#pragma unroll
    for (int r = 0; r < 8; ++r) {
      float4 pv = *(const float4*)&s_lds[r][m];
      pacc[r] += pv.x * vv0 + pv.y * vv1 + pv.z * vv2 + pv.w * vv3;
    }
  }
#pragma unroll
  for (int r = 0; r < 8; ++r) {
    int bl = b * 512 + (l0 + r);
    a2[((size_t)(bl * 8 + c) << 11) + (n << 8) + d] = pacc[r] * rinv[r];
  }
}

extern "C" void kernel_launch(void* const* d_in, const int* in_sizes, int n_in,
                              void* d_out, int out_size, void* d_ws, size_t ws_size,
                              hipStream_t stream) {
  const float* x    = (const float*)d_in[0];
  const float* prev = (const float*)d_in[1];
  const float* cqw  = (const float*)d_in[2];
  const float* ckw  = (const float*)d_in[3];
  const float* cvw  = (const float*)d_in[4];
  const float* wq   = (const float*)d_in[5];
  const float* wk   = (const float*)d_in[6];
  const float* wv   = (const float*)d_in[7];
  const float* wo   = (const float*)d_in[8];

  float* out    = (float*)d_out;             // [2,8,512,256,8]
  float* qk_out = out + 16777216;            // [2,8,8,512,512]

  float* ws      = (float*)d_ws;
  float* wt      = ws;                       // 4 * 524288 transposed weights
  float* convbuf = ws + 2097152;             // 16.7M, reused as a2 after attn
  float* qb      = convbuf + 16777216;
  float* kb      = qb + 16777216;
  float* vb      = kb + 16777216;
  // total ws use: (2097152 + 4*16777216)*4 B ≈ 277 MB

  transpose_w_kernel<<<dim3(2048, 4), 256, 0, stream>>>(wq, wk, wv, wo, wt);

  conv_kernel<<<65536, 256, 0, stream>>>(x, cqw, convbuf);
  mlin_kernel<0><<<8192, 256, 0, stream>>>(convbuf, wt + 0, qb);

  conv_kernel<<<65536, 256, 0, stream>>>(x, ckw, convbuf);
  mlin_kernel<0><<<8192, 256, 0, stream>>>(convbuf, wt + 524288, kb);

  conv_kernel<<<65536, 256, 0, stream>>>(x, cvw, convbuf);
  mlin_kernel<0><<<8192, 256, 0, stream>>>(convbuf, wt + 1048576, vb);

  rope_kernel<<<4096, 256, 0, stream>>>(qb);
  rope_kernel<<<4096, 256, 0, stream>>>(kb);

  attn_kernel<<<8192, 256, 0, stream>>>(qb, kb, vb, prev, qk_out, convbuf);

  mlin_kernel<1><<<8192, 256, 0, stream>>>(convbuf, wt + 1572864, out);
}

// Round 2
// 1121.571 us; speedup vs baseline: 3.0191x; 3.0191x over previous
//
#include <hip/hip_runtime.h>
#include <cstddef>
#include <cstdint>

// B=2, C=8, L=512, CH=256, CW=8, NH=8, D=256, ROT=32. 128 heads total.
// head = (b*8+c)*8+n ; q/k/v bf16 [head][l][256] ; vt bf16 [head][d][512]

typedef unsigned short u16;
typedef unsigned int u32;
typedef __attribute__((ext_vector_type(8))) short short8;
typedef __attribute__((ext_vector_type(4))) float floatx4;

__device__ __forceinline__ float bf2f(u16 u) {
  union { u32 i; float f; } v; v.i = ((u32)u) << 16; return v.f;
}
__device__ __forceinline__ u16 f2bf(float f) {
  union { float f; u32 i; } v; v.f = f;
  return (u16)((v.i + 0x7fffu + ((v.i >> 16) & 1u)) >> 16);
}

// ---------------- weight transpose: wt[c][h][g] = w[c][g][h] ----------------
__global__ __launch_bounds__(256) void transpose_w_kernel(
    const float* __restrict__ wq, const float* __restrict__ wk,
    const float* __restrict__ wv, const float* __restrict__ wo,
    float* __restrict__ wt) {
  int mat = blockIdx.y;
  const float* src = (mat == 0) ? wq : (mat == 1) ? wk : (mat == 2) ? wv : wo;
  float* dst = wt + (size_t)mat * 524288;
  int idx = blockIdx.x * 256 + threadIdx.x;
  int c = idx >> 16, h = (idx >> 8) & 255, g = idx & 255;
  dst[idx] = src[((size_t)c << 16) + (g << 8) + h];
}

// ------------- fused conv: q,k,v convs in one pass, bf16 out ----------------
// block = (bl, ihalf); thread: i = ih*128 + (t&127), sh = t>>7 covers 12 (s,co)
__global__ __launch_bounds__(256) void conv_fused_kernel(
    const float* __restrict__ x,
    const float* __restrict__ wq, const float* __restrict__ wk,
    const float* __restrict__ wv,
    u16* __restrict__ oq, u16* __restrict__ ok, u16* __restrict__ ov) {
  __shared__ float wl[1728];
  int t = threadIdx.x;
  for (int i2 = t; i2 < 1728; i2 += 256)
    wl[i2] = (i2 < 576) ? wq[i2] : (i2 < 1152 ? wk[i2 - 576] : wv[i2 - 1152]);
  __syncthreads();

  int bl = blockIdx.x >> 1, ih = blockIdx.x & 1;
  int b = bl >> 9, l = bl & 511;
  int il = t & 127, sh = t >> 7;
  int i = ih * 128 + il;

  float acc[12][8];
#pragma unroll
  for (int p = 0; p < 12; ++p)
#pragma unroll
    for (int j = 0; j < 8; ++j) acc[p][j] = 0.f;

  for (int ci = 0; ci < 8; ++ci) {
    const float* xc = x + (((size_t)(b * 8 + ci) * 512 + l) << 11);
    float xr[3][10];
#pragma unroll
    for (int di = 0; di < 3; ++di) {
      int gi = i + di - 1;
      xr[di][0] = 0.f; xr[di][9] = 0.f;
      if (gi >= 0 && gi < 256) {
        float4 a = *(const float4*)(xc + gi * 8);
        float4 bq = *(const float4*)(xc + gi * 8 + 4);
        xr[di][1] = a.x; xr[di][2] = a.y; xr[di][3] = a.z; xr[di][4] = a.w;
        xr[di][5] = bq.x; xr[di][6] = bq.y; xr[di][7] = bq.z; xr[di][8] = bq.w;
      } else {
#pragma unroll
        for (int j = 1; j < 9; ++j) xr[di][j] = 0.f;
      }
    }
#pragma unroll
    for (int p = 0; p < 12; ++p) {
      int pp = sh * 12 + p;
      int s = pp >> 3, co = pp & 7;
      const float* wp = &wl[s * 576 + (co * 8 + ci) * 9];
      float w00 = wp[0], w01 = wp[1], w02 = wp[2];
      float w10 = wp[3], w11 = wp[4], w12 = wp[5];
      float w20 = wp[6], w21 = wp[7], w22 = wp[8];
#pragma unroll
      for (int j = 0; j < 8; ++j) {
        acc[p][j] += w00 * xr[0][j] + w01 * xr[0][j + 1] + w02 * xr[0][j + 2]
                   + w10 * xr[1][j] + w11 * xr[1][j + 1] + w12 * xr[1][j + 2]
                   + w20 * xr[2][j] + w21 * xr[2][j + 1] + w22 * xr[2][j + 2];
      }
    }
  }
#pragma unroll
  for (int p = 0; p < 12; ++p) {
    int pp = sh * 12 + p;
    int s = pp >> 3, co = pp & 7;
    u16* ob = (s == 0) ? oq : (s == 1) ? ok : ov;
    uint4 o;
    o.x = (u32)f2bf(acc[p][0]) | ((u32)f2bf(acc[p][1]) << 16);
    o.y = (u32)f2bf(acc[p][2]) | ((u32)f2bf(acc[p][3]) << 16);
    o.z = (u32)f2bf(acc[p][4]) | ((u32)f2bf(acc[p][5]) << 16);
    o.w = (u32)f2bf(acc[p][6]) | ((u32)f2bf(acc[p][7]) << 16);
    *(uint4*)&ob[(((size_t)(bl * 8 + co)) << 11) + i * 8] = o;
  }
}

// ---------------- mlin: 4 bl rows per block, c fixed ------------------------
// MODE 0: bf16 head layout + RoPE (q,k). MODE 1: bf16 head layout (v).
// MODE 2: fp32 direct output [b,c,l,2048].
template <int MODE>
__global__ __launch_bounds__(256) void mlin_kernel(const u16* __restrict__ in,
                                                   const float* __restrict__ wt,
                                                   void* __restrict__ out) {
  __shared__ float lds[4 * 2304];  // staging uses 4*2048; scratch 4*2304
  int tid = threadIdx.x;
  int c = blockIdx.x & 7, blg = blockIdx.x >> 3;  // blg 0..255, bl = blg*4+bb

#pragma unroll
  for (int it = 0; it < 4; ++it) {
    int li = it * 256 + tid;          // uint4 units, 1024 total
    int bb = li >> 8, seg = li & 255;
    uint4 u = *(const uint4*)(in + (((size_t)((blg * 4 + bb) * 8 + c)) << 11) + seg * 8);
    float4 f0, f1;
    f0.x = bf2f(u.x & 0xffff); f0.y = bf2f(u.x >> 16);
    f0.z = bf2f(u.y & 0xffff); f0.w = bf2f(u.y >> 16);
    f1.x = bf2f(u.z & 0xffff); f1.y = bf2f(u.z >> 16);
    f1.z = bf2f(u.w & 0xffff); f1.w = bf2f(u.w >> 16);
    *(float4*)&lds[bb * 2048 + seg * 8] = f0;
    *(float4*)&lds[bb * 2048 + seg * 8 + 4] = f1;
  }
  __syncthreads();

  int g = tid;
  const float* wtc = wt + ((size_t)c << 16) + g;
  float acc[4][8];
#pragma unroll
  for (int bb = 0; bb < 4; ++bb)
#pragma unroll
    for (int w = 0; w < 8; ++w) acc[bb][w] = 0.f;

  for (int h = 0; h < 256; ++h) {
    float wv = wtc[h << 8];
#pragma unroll
    for (int bb = 0; bb < 4; ++bb) {
      float4 i0 = *(const float4*)&lds[bb * 2048 + h * 8];
      float4 i1 = *(const float4*)&lds[bb * 2048 + h * 8 + 4];
      acc[bb][0] += i0.x * wv; acc[bb][1] += i0.y * wv;
      acc[bb][2] += i0.z * wv; acc[bb][3] += i0.w * wv;
      acc[bb][4] += i1.x * wv; acc[bb][5] += i1.y * wv;
      acc[bb][6] += i1.z * wv; acc[bb][7] += i1.w * wv;
    }
  }
  __syncthreads();
#pragma unroll
  for (int bb = 0; bb < 4; ++bb)
#pragma unroll
    for (int w = 0; w < 8; ++w) lds[bb * 2304 + g * 9 + w] = acc[bb][w];
  __syncthreads();

#pragma unroll
  for (int it = 0; it < 32; ++it) {
    int li = it * 256 + tid;
    int bb = li >> 11, tt = li & 2047;
    float val = lds[bb * 2304 + (tt >> 3) * 9 + (tt & 7)];
    int bl = blg * 4 + bb;
    int b = bl >> 9, l = bl & 511;
    if (MODE == 2) {
      ((float*)out)[(((size_t)((b * 8 + c) * 512 + l)) << 11) + tt] = val;
    } else {
      int n = tt >> 8, d = tt & 255;
      if (MODE == 0 && d < 32) {
        int p = d >> 1;
        int f0i = (n << 8) + (p << 1);
        float x0 = lds[bb * 2304 + (f0i >> 3) * 9 + (f0i & 7)];
        float x1 = lds[bb * 2304 + ((f0i + 1) >> 3) * 9 + ((f0i + 1) & 7)];
        float ang = (float)l * __expf(-(float)p * 0.57564627324851142f); // ln(1e4)/16
        float cv = cosf(ang), sv = sinf(ang);
        val = (d & 1) ? (x1 * cv + x0 * sv) : (x0 * cv - x1 * sv);
      }
      ((u16*)out)[(((size_t)((b * 8 + c) * 8 + n)) << 17) + (l << 8) + d] = f2bf(val);
    }
  }
}

// ---------------- V transpose: vt[head][d][m] = vb[head][m][d] --------------
__global__ __launch_bounds__(256) void transpose_v_kernel(const u16* __restrict__ vb,
                                                          u16* __restrict__ vt) {
  __shared__ u16 tile[64 * 66];
  int bx = blockIdx.x;                  // head*32 + mt*4 + dt
  int head = bx >> 5, mt = (bx >> 2) & 7, dt = bx & 3;
  size_t off = (size_t)head << 17;
  int t = threadIdx.x;
#pragma unroll
  for (int it = 0; it < 2; ++it) {
    int li = it * 256 + t;
    int r = li >> 3, cs = li & 7;
    uint4 u = *(const uint4*)(vb + off + (size_t)(mt * 64 + r) * 256 + dt * 64 + cs * 8);
    *(u32*)&tile[r * 66 + cs * 8 + 0] = u.x;
    *(u32*)&tile[r * 66 + cs * 8 + 2] = u.y;
    *(u32*)&tile[r * 66 + cs * 8 + 4] = u.z;
    *(u32*)&tile[r * 66 + cs * 8 + 6] = u.w;
  }
  __syncthreads();
#pragma unroll
  for (int it = 0; it < 2; ++it) {
    int li = it * 256 + t;
    int r = li >> 3, cs = li & 7;   // r = d-local, cs = m-seg
    u16 tmp[8];
#pragma unroll
    for (int jj = 0; jj < 8; ++jj) tmp[jj] = tile[(cs * 8 + jj) * 66 + r];
    uint4 o;
    o.x = (u32)tmp[0] | ((u32)tmp[1] << 16);
    o.y = (u32)tmp[2] | ((u32)tmp[3] << 16);
    o.z = (u32)tmp[4] | ((u32)tmp[5] << 16);
    o.w = (u32)tmp[6] | ((u32)tmp[7] << 16);
    *(uint4*)(vt + off + (size_t)(dt * 64 + r) * 512 + mt * 64 + cs * 8) = o;
  }
}

// ---------------- MFMA attention: 32 q-rows per block -----------------------
__global__ __launch_bounds__(256) void attn_kernel(
    const u16* __restrict__ q, const u16* __restrict__ k,
    const u16* __restrict__ vt, const float* __restrict__ prev,
    float* __restrict__ qk_out, u16* __restrict__ a2) {
  __shared__ u16 s_bf[32 * 520];      // S / P, bf16, stride 520 (4x65 words)
  __shared__ u16 kv[32 * 288];        // K chunk (32x288) / V chunk (256x32)
  __shared__ float rinv[32];

  int head = blockIdx.x >> 4;
  int l0 = (blockIdx.x & 15) << 5;
  int b = head >> 6, c = (head >> 3) & 7, nh = head & 7;
  size_t qoff = (size_t)head << 17;
  size_t poff = (size_t)head << 18;
  int tid = threadIdx.x;
  int w = tid >> 6, lane = tid & 63;
  int fn = lane & 15, fq = lane >> 4;
  int rt = w & 1, ct = w >> 1;

  // preload Q fragments (16 rows for this wave, full K=256)
  short8 qf[8];
  const u16* qrow = q + qoff + (size_t)(l0 + rt * 16 + fn) * 256 + fq * 8;
#pragma unroll
  for (int kc = 0; kc < 8; ++kc) qf[kc] = *(const short8*)(qrow + kc * 32);

  // ---- S = QK^T/16 + prev ----
  for (int mc = 0; mc < 16; ++mc) {
    int m0 = mc * 32;
#pragma unroll
    for (int it = 0; it < 4; ++it) {
      int li = it * 256 + tid;
      int m = li >> 5, ds = li & 31;
      *(uint4*)&kv[m * 288 + ds * 8] =
          *(const uint4*)(k + qoff + (size_t)(m0 + m) * 256 + ds * 8);
    }
    __syncthreads();
    floatx4 acc = {0.f, 0.f, 0.f, 0.f};
    const u16* krow = &kv[(ct * 16 + fn) * 288 + fq * 8];
#pragma unroll
    for (int kc = 0; kc < 8; ++kc) {
      short8 bfr = *(const short8*)(krow + kc * 32);
      acc = __builtin_amdgcn_mfma_f32_16x16x32_bf16(qf[kc], bfr, acc, 0, 0, 0);
    }
#pragma unroll
    for (int r = 0; r < 4; ++r) {
      int lrow = rt * 16 + fq * 4 + r;
      int mcol = m0 + ct * 16 + fn;
      size_t gi = poff + (size_t)(l0 + lrow) * 512 + mcol;
      float sv = acc[r] * 0.0625f + prev[gi];
      qk_out[gi] = sv;
      s_bf[lrow * 520 + mcol] = f2bf(sv);
    }
    __syncthreads();
  }

  // ---- softmax over rows (8 threads per row) ----
  {
    int srow = tid >> 3, sseg = tid & 7;
    u16* sp = &s_bf[srow * 520 + sseg * 64];
    float mx = -1e30f;
#pragma unroll
    for (int ii = 0; ii < 8; ++ii) {
      uint4 u = *(const uint4*)(sp + ii * 8);
      mx = fmaxf(mx, fmaxf(fmaxf(fmaxf(bf2f(u.x & 0xffff), bf2f(u.x >> 16)),
                                 fmaxf(bf2f(u.y & 0xffff), bf2f(u.y >> 16))),
                           fmaxf(fmaxf(bf2f(u.z & 0xffff), bf2f(u.z >> 16)),
                                 fmaxf(bf2f(u.w & 0xffff), bf2f(u.w >> 16)))));
    }
#pragma unroll
    for (int o = 1; o < 8; o <<= 1) mx = fmaxf(mx, __shfl_xor(mx, o));
    float sum = 0.f;
#pragma unroll
    for (int ii = 0; ii < 8; ++ii) {
      uint4 u = *(const uint4*)(sp + ii * 8);
      float e0 = __expf(bf2f(u.x & 0xffff) - mx), e1 = __expf(bf2f(u.x >> 16) - mx);
      float e2 = __expf(bf2f(u.y & 0xffff) - mx), e3 = __expf(bf2f(u.y >> 16) - mx);
      float e4 = __expf(bf2f(u.z & 0xffff) - mx), e5 = __expf(bf2f(u.z >> 16) - mx);
      float e6 = __expf(bf2f(u.w & 0xffff) - mx), e7 = __expf(bf2f(u.w >> 16) - mx);
      sum += e0 + e1 + e2 + e3 + e4 + e5 + e6 + e7;
      uint4 o;
      o.x = (u32)f2bf(e0) | ((u32)f2bf(e1) << 16);
      o.y = (u32)f2bf(e2) | ((u32)f2bf(e3) << 16);
      o.z = (u32)f2bf(e4) | ((u32)f2bf(e5) << 16);
      o.w = (u32)f2bf(e6) | ((u32)f2bf(e7) << 16);
      *(uint4*)(sp + ii * 8) = o;
    }
#pragma unroll
    for (int o = 1; o < 8; o <<= 1) sum += __shfl_xor(sum, o);
    if (sseg == 0) rinv[srow] = 1.0f / sum;
  }

  // ---- O = P V ----
  floatx4 oacc[8];
#pragma unroll
  for (int dt = 0; dt < 8; ++dt) oacc[dt] = (floatx4){0.f, 0.f, 0.f, 0.f};

  for (int mc = 0; mc < 16; ++mc) {
    int m0 = mc * 32;
#pragma unroll
    for (int it = 0; it < 4; ++it) {
      int li = it * 256 + tid;
      int d = li >> 2, ms = li & 3;
      *(uint4*)&kv[d * 32 + ms * 8] =
          *(const uint4*)(vt + qoff + (size_t)d * 512 + m0 + ms * 8);
    }
    __syncthreads();
    short8 af = *(const short8*)&s_bf[(rt * 16 + fn) * 520 + m0 + fq * 8];
#pragma unroll
    for (int dt = 0; dt < 8; ++dt) {
      int d0 = ct * 128 + dt * 16;
      short8 bfr = *(const short8*)&kv[(d0 + fn) * 32 + fq * 8];
      oacc[dt] = __builtin_amdgcn_mfma_f32_16x16x32_bf16(af, bfr, oacc[dt], 0, 0, 0);
    }
    __syncthreads();
  }

  float riv[4];
#pragma unroll
  for (int r = 0; r < 4; ++r) riv[r] = rinv[rt * 16 + fq * 4 + r];
#pragma unroll
  for (int dt = 0; dt < 8; ++dt) {
#pragma unroll
    for (int r = 0; r < 4; ++r) {
      int lrow = l0 + rt * 16 + fq * 4 + r;
      int d = ct * 128 + dt * 16 + fn;
      int bl = b * 512 + lrow;
      a2[(size_t)(bl * 8 + c) * 2048 + nh * 256 + d] = f2bf(oacc[dt][r] * riv[r]);
    }
  }
}

extern "C" void kernel_launch(void* const* d_in, const int* in_sizes, int n_in,
                              void* d_out, int out_size, void* d_ws, size_t ws_size,
                              hipStream_t stream) {
  const float* x    = (const float*)d_in[0];
  const float* prev = (const float*)d_in[1];
  const float* cqw  = (const float*)d_in[2];
  const float* ckw  = (const float*)d_in[3];
  const float* cvw  = (const float*)d_in[4];
  const float* wq   = (const float*)d_in[5];
  const float* wk   = (const float*)d_in[6];
  const float* wv   = (const float*)d_in[7];
  const float* wo   = (const float*)d_in[8];

  float* out    = (float*)d_out;
  float* qk_out = out + 16777216;

  char* wsb = (char*)d_ws;
  float* wt   = (float*)wsb;                       // 8 MB
  u16* convq  = (u16*)(wsb + 8388608);             // each 33.5 MB
  u16* convk  = convq + 16777216;
  u16* convv  = convk + 16777216;
  u16* qb     = convv + 16777216;
  u16* kb     = qb + 16777216;
  u16* vb     = kb + 16777216;
  u16* vtb    = vb + 16777216;
  u16* a2     = vtb + 16777216;
  // total ~277 MB

  transpose_w_kernel<<<dim3(2048, 4), 256, 0, stream>>>(wq, wk, wv, wo, wt);
  conv_fused_kernel<<<2048, 256, 0, stream>>>(x, cqw, ckw, cvw, convq, convk, convv);
  mlin_kernel<0><<<2048, 256, 0, stream>>>(convq, wt + 0, qb);
  mlin_kernel<0><<<2048, 256, 0, stream>>>(convk, wt + 524288, kb);
  mlin_kernel<1><<<2048, 256, 0, stream>>>(convv, wt + 1048576, vb);
  transpose_v_kernel<<<4096, 256, 0, stream>>>(vb, vtb);
  attn_kernel<<<2048, 256, 0, stream>>>(qb, kb, vtb, prev, qk_out, a2);
  mlin_kernel<2><<<2048, 256, 0, stream>>>(a2, wt + 1572864, out);
}